// Round 1
// baseline (938.795 us; speedup 1.0000x reference)
//
#include <hip/hip_runtime.h>
#include <hip/hip_bf16.h>

#define N_FLOWS 50000
#define N_LINKS 5000
#define LPATH 8
#define PLINK 80
#define DIM 16
#define ITERS 12

__device__ __forceinline__ float sigmoid_(float x) { return 1.f / (1.f + __expf(-x)); }
__device__ __forceinline__ float tanh_(float x) { return 1.f - 2.f / (1.f + __expf(2.f * x)); }
__device__ __forceinline__ float selu_(float x) {
    const float sc = 1.0507009873554805f, al = 1.6732632423543772f;
    return x > 0.f ? sc * x : sc * al * expm1f(x);
}
__device__ __forceinline__ float softplus_(float x) {
    return fmaxf(x, 0.f) + log1pf(__expf(-fabsf(x)));
}

// ---- load per link: sum of gathered flow_traffic / (cap*1e9) -------------
__global__ __launch_bounds__(256) void k_load(const int* __restrict__ p2l,
                                              const float* __restrict__ flow_traffic,
                                              const float* __restrict__ link_capacity,
                                              float* __restrict__ load) {
    int wave = (blockIdx.x * 256 + threadIdx.x) >> 6;
    int lane = threadIdx.x & 63;
    if (wave >= N_LINKS) return;
    float s = 0.f;
    for (int p = lane; p < PLINK; p += 64) {
        int flow = p2l[(wave * PLINK + p) * 2];
        s += flow_traffic[flow];
    }
#pragma unroll
    for (int off = 32; off; off >>= 1) s += __shfl_xor(s, off, 64);
    if (lane == 0) load[wave] = s / (link_capacity[wave] * 1e9f);
}

// ---- flow embedding: feats(13) -> selu -> selu -> path_state(16) ---------
__global__ __launch_bounds__(256) void k_flow_init(
    const float* __restrict__ flow_traffic, const float* __restrict__ flow_packets,
    const float* __restrict__ ibg, const float* __restrict__ rate,
    const float* __restrict__ p90, const float* __restrict__ pkt_size,
    const float* __restrict__ bitrate_pb, const float* __restrict__ ipg_mean,
    const float* __restrict__ ipg_var, const float* __restrict__ pkts_pb,
    const int* __restrict__ flow_length, const float* __restrict__ flow_type,
    const float* __restrict__ W1, const float* __restrict__ b1,
    const float* __restrict__ W2, const float* __restrict__ b2,
    float* __restrict__ path_state) {
    int f = blockIdx.x * 256 + threadIdx.x;
    if (f >= N_FLOWS) return;
    float feats[13];
    feats[0] = (flow_traffic[f] - 0.1f) * 2.f;
    feats[1] = (flow_packets[f] - 0.1f) * 2.f;
    feats[2] = (ibg[f] - 0.1f) * 2.f;
    feats[3] = (rate[f] - 0.1f) * 2.f;
    feats[4] = (p90[f] - 0.1f) * 2.f;
    feats[5] = (pkt_size[f] - 0.1f) * 2.f;
    feats[6] = (bitrate_pb[f] - 0.1f) * 2.f;
    feats[7] = (ipg_mean[f] - 0.1f) * 2.f;
    feats[8] = (ipg_var[f] - 0.1f) * 2.f;
    feats[9] = (pkts_pb[f] - 0.1f) * 2.f;
    feats[10] = (float)flow_length[f];
    feats[11] = flow_type[f * 2 + 0];
    feats[12] = flow_type[f * 2 + 1];
    float h1[DIM];
#pragma unroll
    for (int j = 0; j < DIM; ++j) {
        float a = b1[j];
#pragma unroll
        for (int k = 0; k < 13; ++k) a = fmaf(feats[k], W1[k * DIM + j], a);
        h1[j] = selu_(a);
    }
#pragma unroll
    for (int j = 0; j < DIM; ++j) {
        float a = b2[j];
#pragma unroll
        for (int k = 0; k < DIM; ++k) a = fmaf(h1[k], W2[k * DIM + j], a);
        path_state[f * DIM + j] = selu_(a);
    }
}

// ---- link embedding: feats(3) -> selu -> selu -> link_state(16) ----------
__global__ __launch_bounds__(256) void k_link_init(
    const float* __restrict__ link_capacity, const float* __restrict__ load,
    const float* __restrict__ max_link_load,
    const float* __restrict__ W1, const float* __restrict__ b1,
    const float* __restrict__ W2, const float* __restrict__ b2,
    float* __restrict__ link_state) {
    int l = blockIdx.x * 256 + threadIdx.x;
    if (l >= N_LINKS) return;
    float feats[3];
    feats[0] = (link_capacity[l] - 0.1f) * 2.f;
    feats[1] = load[l];
    feats[2] = load[l] / max_link_load[0];
    float h1[DIM];
#pragma unroll
    for (int j = 0; j < DIM; ++j) {
        float a = b1[j];
#pragma unroll
        for (int k = 0; k < 3; ++k) a = fmaf(feats[k], W1[k * DIM + j], a);
        h1[j] = selu_(a);
    }
#pragma unroll
    for (int j = 0; j < DIM; ++j) {
        float a = b2[j];
#pragma unroll
        for (int k = 0; k < DIM; ++k) a = fmaf(h1[k], W2[k * DIM + j], a);
        link_state[l * DIM + j] = selu_(a);
    }
}

// ---- flow pass: gather link states, GRU scan over L=8, write sequence ----
// 16 lanes per flow; lane j holds hidden component j and weight columns j/j+16/j+32.
__global__ __launch_bounds__(256) void k_flow_pass(
    const int* __restrict__ l2p, const float* __restrict__ link_state,
    float* __restrict__ path_state, float* __restrict__ seq,
    const float* __restrict__ Wk, const float* __restrict__ Wr,
    const float* __restrict__ b) {
    int tid = blockIdx.x * 256 + threadIdx.x;
    int f = tid >> 4;
    int j = tid & 15;
    if (f >= N_FLOWS) return;
    float wkz[16], wkr[16], wkh[16], wrz[16], wrr[16], wrh[16];
#pragma unroll
    for (int k = 0; k < 16; ++k) {
        wkz[k] = Wk[k * 48 + j];
        wkr[k] = Wk[k * 48 + 16 + j];
        wkh[k] = Wk[k * 48 + 32 + j];
        wrz[k] = Wr[k * 48 + j];
        wrr[k] = Wr[k * 48 + 16 + j];
        wrh[k] = Wr[k * 48 + 32 + j];
    }
    float b0z = b[j], b0r = b[16 + j], b0h = b[32 + j];
    float b1z = b[48 + j], b1r = b[64 + j], b1h = b[80 + j];
    float h = path_state[f * DIM + j];
    seq[f * (LPATH + 1) * DIM + j] = h;  // prev_path_state at t=0
    for (int t = 0; t < LPATH; ++t) {
        int link = l2p[f * LPATH + t];
        float x = link_state[link * DIM + j];
        float az = b0z, ar = b0r, ah = b0h, gz = b1z, gr = b1r, gh = b1h;
#pragma unroll
        for (int k = 0; k < 16; ++k) {
            float xb = __shfl(x, k, 16);
            float hb = __shfl(h, k, 16);
            az = fmaf(xb, wkz[k], az);
            ar = fmaf(xb, wkr[k], ar);
            ah = fmaf(xb, wkh[k], ah);
            gz = fmaf(hb, wrz[k], gz);
            gr = fmaf(hb, wrr[k], gr);
            gh = fmaf(hb, wrh[k], gh);
        }
        float z = sigmoid_(az + gz);
        float r = sigmoid_(ar + gr);
        float cand = tanh_(fmaf(r, gh, ah));
        h = z * h + (1.f - z) * cand;
        seq[f * (LPATH + 1) * DIM + (t + 1) * DIM + j] = h;
    }
    path_state[f * DIM + j] = h;
}

// ---- link pass: attention over 80 gathered path states + link GRU --------
// one block (256 thr = 16 groups x 16 lanes) per link.
__global__ __launch_bounds__(256) void k_link_pass(
    const int* __restrict__ p2l, const float* __restrict__ seq,
    float* __restrict__ link_state,
    const float* __restrict__ attW, const float* __restrict__ attB,
    const float* __restrict__ Wk, const float* __restrict__ Wr,
    const float* __restrict__ b) {
    int link = blockIdx.x;
    int tid = threadIdx.x;
    int g = tid >> 4, j = tid & 15;
    __shared__ float red[16][17];
    float wa[16];
#pragma unroll
    for (int k = 0; k < 16; ++k) wa[k] = attW[k * DIM + j];
    float ab = attB[j];
    float acc = 0.f;
#pragma unroll
    for (int pp = 0; pp < PLINK / 16; ++pp) {
        int p = g + pp * 16;
        int flow = p2l[(link * PLINK + p) * 2 + 0];
        int pos = p2l[(link * PLINK + p) * 2 + 1];
        float pg = seq[flow * (LPATH + 1) * DIM + pos * DIM + j];
        float att = ab;
#pragma unroll
        for (int k = 0; k < 16; ++k) att = fmaf(__shfl(pg, k, 16), wa[k], att);
        att = att > 0.f ? att : 0.01f * att;  // leaky_relu
        float m = att;
#pragma unroll
        for (int off = 8; off; off >>= 1) m = fmaxf(m, __shfl_xor(m, off, 16));
        float e = __expf(att - m);
        float s = e;
#pragma unroll
        for (int off = 8; off; off >>= 1) s += __shfl_xor(s, off, 16);
        acc = fmaf(e / s, pg, acc);
    }
    red[g][j] = acc;
    __syncthreads();
    if (tid < 16) {
        float ps = 0.f;
#pragma unroll
        for (int gg = 0; gg < 16; ++gg) ps += red[gg][j];
        float h = link_state[link * DIM + j];
        float az = b[j], ar = b[16 + j], ah = b[32 + j];
        float gz = b[48 + j], gr = b[64 + j], gh = b[80 + j];
#pragma unroll
        for (int k = 0; k < 16; ++k) {
            float xb = __shfl(ps, k, 16);
            float hb = __shfl(h, k, 16);
            az = fmaf(xb, Wk[k * 48 + j], az);
            ar = fmaf(xb, Wk[k * 48 + 16 + j], ar);
            ah = fmaf(xb, Wk[k * 48 + 32 + j], ah);
            gz = fmaf(hb, Wr[k * 48 + j], gz);
            gr = fmaf(hb, Wr[k * 48 + 16 + j], gr);
            gh = fmaf(hb, Wr[k * 48 + 32 + j], gh);
        }
        float z = sigmoid_(az + gz);
        float r = sigmoid_(ar + gr);
        float cand = tanh_(fmaf(r, gh, ah));
        link_state[link * DIM + j] = z * h + (1.f - z) * cand;
    }
}

// ---- readout: MLP over seq[:,1:] -> softplus -> /cap -> sum over L -------
// 8 lanes per flow (one per t), shuffle-reduce over width 8.
__global__ __launch_bounds__(256) void k_readout(
    const float* __restrict__ seq, const int* __restrict__ l2p,
    const float* __restrict__ link_capacity,
    const float* __restrict__ W1, const float* __restrict__ b1,
    const float* __restrict__ W2, const float* __restrict__ b2,
    const float* __restrict__ W3, const float* __restrict__ b3,
    float* __restrict__ out) {
    int tid = blockIdx.x * 256 + threadIdx.x;
    int f = tid >> 3;
    int t = tid & 7;  // handles sequence position t+1
    if (f >= N_FLOWS) return;
    const float* s = seq + f * (LPATH + 1) * DIM + (t + 1) * DIM;
    float h1[8];
#pragma unroll
    for (int m = 0; m < 8; ++m) {
        float a = b1[m];
#pragma unroll
        for (int k = 0; k < 16; ++k) a = fmaf(s[k], W1[k * 8 + m], a);
        h1[m] = selu_(a);
    }
    float h2[4];
#pragma unroll
    for (int q = 0; q < 4; ++q) {
        float a = b2[q];
#pragma unroll
        for (int m = 0; m < 8; ++m) a = fmaf(h1[m], W2[m * 4 + q], a);
        h2[q] = selu_(a);
    }
    float o = b3[0];
#pragma unroll
    for (int q = 0; q < 4; ++q) o = fmaf(h2[q], W3[q], o);
    o = softplus_(o);
    int link = l2p[f * LPATH + t];
    float v = o / link_capacity[link];
#pragma unroll
    for (int off = 4; off; off >>= 1) v += __shfl_xor(v, off, 8);
    if (t == 0) out[f] = v;
}

extern "C" void kernel_launch(void* const* d_in, const int* in_sizes, int n_in,
                              void* d_out, int out_size, void* d_ws, size_t ws_size,
                              hipStream_t stream) {
    const float* flow_traffic = (const float*)d_in[0];
    const float* flow_packets = (const float*)d_in[1];
    const float* max_link_load = (const float*)d_in[2];
    const float* flow_pkts_per_burst = (const float*)d_in[3];
    const float* flow_bitrate_per_burst = (const float*)d_in[4];
    const float* flow_packet_size = (const float*)d_in[5];
    const float* flow_type = (const float*)d_in[6];
    const float* flow_ipg_mean = (const float*)d_in[7];
    const float* ibg = (const float*)d_in[8];
    const float* flow_p90 = (const float*)d_in[9];
    const float* rate = (const float*)d_in[10];
    const float* flow_ipg_var = (const float*)d_in[11];
    const float* link_capacity = (const float*)d_in[12];
    const float* fe_W1 = (const float*)d_in[13];
    const float* fe_b1 = (const float*)d_in[14];
    const float* fe_W2 = (const float*)d_in[15];
    const float* fe_b2 = (const float*)d_in[16];
    const float* le_W1 = (const float*)d_in[17];
    const float* le_b1 = (const float*)d_in[18];
    const float* le_W2 = (const float*)d_in[19];
    const float* le_b2 = (const float*)d_in[20];
    const float* att_W = (const float*)d_in[21];
    const float* att_b = (const float*)d_in[22];
    const float* pgru_Wk = (const float*)d_in[23];
    const float* pgru_Wr = (const float*)d_in[24];
    const float* pgru_b = (const float*)d_in[25];
    const float* lgru_Wk = (const float*)d_in[26];
    const float* lgru_Wr = (const float*)d_in[27];
    const float* lgru_b = (const float*)d_in[28];
    const float* ro_W1 = (const float*)d_in[29];
    const float* ro_b1 = (const float*)d_in[30];
    const float* ro_W2 = (const float*)d_in[31];
    const float* ro_b2 = (const float*)d_in[32];
    const float* ro_W3 = (const float*)d_in[33];
    const float* ro_b3 = (const float*)d_in[34];
    const int* flow_length = (const int*)d_in[35];
    const int* l2p = (const int*)d_in[36];
    const int* p2l = (const int*)d_in[37];

    float* ws = (float*)d_ws;
    float* path_state = ws;                      // 800000
    float* link_state = ws + 800000;             // 80000
    float* seq = ws + 880000;                    // 7200000
    float* load = ws + 8080000;                  // 5000
    if (ws_size < (size_t)8085000 * 4) return;   // loud failure if ws too small

    k_load<<<(N_LINKS * 64 + 255) / 256, 256, 0, stream>>>(p2l, flow_traffic,
                                                           link_capacity, load);
    k_flow_init<<<(N_FLOWS + 255) / 256, 256, 0, stream>>>(
        flow_traffic, flow_packets, ibg, rate, flow_p90, flow_packet_size,
        flow_bitrate_per_burst, flow_ipg_mean, flow_ipg_var, flow_pkts_per_burst,
        flow_length, flow_type, fe_W1, fe_b1, fe_W2, fe_b2, path_state);
    k_link_init<<<(N_LINKS + 255) / 256, 256, 0, stream>>>(
        link_capacity, load, max_link_load, le_W1, le_b1, le_W2, le_b2, link_state);

    for (int it = 0; it < ITERS; ++it) {
        k_flow_pass<<<N_FLOWS * 16 / 256, 256, 0, stream>>>(
            l2p, link_state, path_state, seq, pgru_Wk, pgru_Wr, pgru_b);
        k_link_pass<<<N_LINKS, 256, 0, stream>>>(
            p2l, seq, link_state, att_W, att_b, lgru_Wk, lgru_Wr, lgru_b);
    }

    k_readout<<<(N_FLOWS * 8 + 255) / 256, 256, 0, stream>>>(
        seq, l2p, link_capacity, ro_W1, ro_b1, ro_W2, ro_b2, ro_W3, ro_b3,
        (float*)d_out);
}

// Round 2
// 724.987 us; speedup vs baseline: 1.2949x; 1.2949x over previous
//
#include <hip/hip_runtime.h>
#include <hip/hip_bf16.h>

#define N_FLOWS 50000
#define N_LINKS 5000
#define LPATH 8
#define PLINK 80
#define DIM 16
#define ITERS 12

__device__ __forceinline__ float sigmoid_(float x) { return 1.f / (1.f + __expf(-x)); }
__device__ __forceinline__ float tanh_(float x) { return 1.f - 2.f / (1.f + __expf(2.f * x)); }
__device__ __forceinline__ float selu_(float x) {
    const float sc = 1.0507009873554805f, al = 1.6732632423543772f;
    return x > 0.f ? sc * x : sc * al * expm1f(x);
}
__device__ __forceinline__ float softplus_(float x) {
    return fmaxf(x, 0.f) + log1pf(__expf(-fabsf(x)));
}

// ---- load per link: sum of gathered flow_traffic / (cap*1e9) -------------
__global__ __launch_bounds__(256) void k_load(const int* __restrict__ p2l,
                                              const float* __restrict__ flow_traffic,
                                              const float* __restrict__ link_capacity,
                                              float* __restrict__ load) {
    int wave = (blockIdx.x * 256 + threadIdx.x) >> 6;
    int lane = threadIdx.x & 63;
    if (wave >= N_LINKS) return;
    float s = 0.f;
    for (int p = lane; p < PLINK; p += 64) {
        int flow = p2l[(wave * PLINK + p) * 2];
        s += flow_traffic[flow];
    }
#pragma unroll
    for (int off = 32; off; off >>= 1) s += __shfl_xor(s, off, 64);
    if (lane == 0) load[wave] = s / (link_capacity[wave] * 1e9f);
}

// ---- flow embedding: feats(13) -> selu -> selu -> path_state(16) ---------
__global__ __launch_bounds__(256) void k_flow_init(
    const float* __restrict__ flow_traffic, const float* __restrict__ flow_packets,
    const float* __restrict__ ibg, const float* __restrict__ rate,
    const float* __restrict__ p90, const float* __restrict__ pkt_size,
    const float* __restrict__ bitrate_pb, const float* __restrict__ ipg_mean,
    const float* __restrict__ ipg_var, const float* __restrict__ pkts_pb,
    const int* __restrict__ flow_length, const float* __restrict__ flow_type,
    const float* __restrict__ W1, const float* __restrict__ b1,
    const float* __restrict__ W2, const float* __restrict__ b2,
    float* __restrict__ path_state) {
    int f = blockIdx.x * 256 + threadIdx.x;
    if (f >= N_FLOWS) return;
    float feats[13];
    feats[0] = (flow_traffic[f] - 0.1f) * 2.f;
    feats[1] = (flow_packets[f] - 0.1f) * 2.f;
    feats[2] = (ibg[f] - 0.1f) * 2.f;
    feats[3] = (rate[f] - 0.1f) * 2.f;
    feats[4] = (p90[f] - 0.1f) * 2.f;
    feats[5] = (pkt_size[f] - 0.1f) * 2.f;
    feats[6] = (bitrate_pb[f] - 0.1f) * 2.f;
    feats[7] = (ipg_mean[f] - 0.1f) * 2.f;
    feats[8] = (ipg_var[f] - 0.1f) * 2.f;
    feats[9] = (pkts_pb[f] - 0.1f) * 2.f;
    feats[10] = (float)flow_length[f];
    feats[11] = flow_type[f * 2 + 0];
    feats[12] = flow_type[f * 2 + 1];
    float h1[DIM];
#pragma unroll
    for (int j = 0; j < DIM; ++j) {
        float a = b1[j];
#pragma unroll
        for (int k = 0; k < 13; ++k) a = fmaf(feats[k], W1[k * DIM + j], a);
        h1[j] = selu_(a);
    }
#pragma unroll
    for (int j = 0; j < DIM; ++j) {
        float a = b2[j];
#pragma unroll
        for (int k = 0; k < DIM; ++k) a = fmaf(h1[k], W2[k * DIM + j], a);
        path_state[f * DIM + j] = selu_(a);
    }
}

// ---- link embedding + xform precompute -----------------------------------
// xform[l][c] = b0[c] + sum_k link_state[l][k] * Wk[k][c]   (c in [0,48))
__global__ __launch_bounds__(256) void k_link_init(
    const float* __restrict__ link_capacity, const float* __restrict__ load,
    const float* __restrict__ max_link_load,
    const float* __restrict__ W1, const float* __restrict__ b1,
    const float* __restrict__ W2, const float* __restrict__ b2,
    const float* __restrict__ pWk, const float* __restrict__ pb,
    float* __restrict__ link_state, float* __restrict__ xform) {
    int l = blockIdx.x * 256 + threadIdx.x;
    if (l >= N_LINKS) return;
    float feats[3];
    feats[0] = (link_capacity[l] - 0.1f) * 2.f;
    feats[1] = load[l];
    feats[2] = load[l] / max_link_load[0];
    float h1[DIM];
#pragma unroll
    for (int j = 0; j < DIM; ++j) {
        float a = b1[j];
#pragma unroll
        for (int k = 0; k < 3; ++k) a = fmaf(feats[k], W1[k * DIM + j], a);
        h1[j] = selu_(a);
    }
    float h2[DIM];
#pragma unroll
    for (int j = 0; j < DIM; ++j) {
        float a = b2[j];
#pragma unroll
        for (int k = 0; k < DIM; ++k) a = fmaf(h1[k], W2[k * DIM + j], a);
        h2[j] = selu_(a);
        link_state[l * DIM + j] = h2[j];
    }
#pragma unroll
    for (int c = 0; c < 3 * DIM; ++c) {
        float a = pb[c];
#pragma unroll
        for (int k = 0; k < DIM; ++k) a = fmaf(h2[k], pWk[k * 48 + c], a);
        xform[l * 48 + c] = a;
    }
}

// ---- flow pass: gather precomputed xform, GRU scan over L=8 --------------
// 16 lanes per flow; lane j holds hidden component j and Wr columns j/j+16/j+32.
__global__ __launch_bounds__(256) void k_flow_pass(
    const int* __restrict__ l2p, const float* __restrict__ xform,
    float* __restrict__ path_state, float* __restrict__ seq,
    const float* __restrict__ Wr, const float* __restrict__ b) {
    int tid = blockIdx.x * 256 + threadIdx.x;
    int f = tid >> 4;
    int j = tid & 15;
    if (f >= N_FLOWS) return;
    float wrz[16], wrr[16], wrh[16];
#pragma unroll
    for (int k = 0; k < 16; ++k) {
        wrz[k] = Wr[k * 48 + j];
        wrr[k] = Wr[k * 48 + 16 + j];
        wrh[k] = Wr[k * 48 + 32 + j];
    }
    float b1z = b[48 + j], b1r = b[64 + j], b1h = b[80 + j];
    int links[LPATH];
#pragma unroll
    for (int t = 0; t < LPATH; ++t) links[t] = l2p[f * LPATH + t];
    float h = path_state[f * DIM + j];
    seq[f * (LPATH + 1) * DIM + j] = h;  // prev_path_state at t=0
    // software prefetch of step-0 xform triple
    float nz = xform[links[0] * 48 + j];
    float nr = xform[links[0] * 48 + 16 + j];
    float nh = xform[links[0] * 48 + 32 + j];
#pragma unroll
    for (int t = 0; t < LPATH; ++t) {
        float az = nz, ar = nr, ah = nh;
        if (t < LPATH - 1) {
            nz = xform[links[t + 1] * 48 + j];
            nr = xform[links[t + 1] * 48 + 16 + j];
            nh = xform[links[t + 1] * 48 + 32 + j];
        }
        float gz = b1z, gr = b1r, gh = b1h;
#pragma unroll
        for (int k = 0; k < 16; ++k) {
            float hb = __shfl(h, k, 16);
            gz = fmaf(hb, wrz[k], gz);
            gr = fmaf(hb, wrr[k], gr);
            gh = fmaf(hb, wrh[k], gh);
        }
        float z = sigmoid_(az + gz);
        float r = sigmoid_(ar + gr);
        float cand = tanh_(fmaf(r, gh, ah));
        h = z * h + (1.f - z) * cand;
        seq[f * (LPATH + 1) * DIM + (t + 1) * DIM + j] = h;
    }
    path_state[f * DIM + j] = h;
}

// ---- link pass: attention over 80 gathered path states + link GRU + xform -
// one block (256 thr = 16 groups x 16 lanes) per link.
__global__ __launch_bounds__(256) void k_link_pass(
    const int* __restrict__ p2l, const float* __restrict__ seq,
    float* __restrict__ link_state,
    const float* __restrict__ attW, const float* __restrict__ attB,
    const float* __restrict__ Wk, const float* __restrict__ Wr,
    const float* __restrict__ b, float* __restrict__ xform) {
    int link = blockIdx.x;
    int tid = threadIdx.x;
    int g = tid >> 4, j = tid & 15;
    __shared__ float red[16][17];
    __shared__ float hsh[16];
    float wa[16];
#pragma unroll
    for (int k = 0; k < 16; ++k) wa[k] = attW[k * DIM + j];
    float ab = attB[j];
    float acc = 0.f;
#pragma unroll
    for (int pp = 0; pp < PLINK / 16; ++pp) {
        int p = g + pp * 16;
        int flow = p2l[(link * PLINK + p) * 2 + 0];
        int pos = p2l[(link * PLINK + p) * 2 + 1];
        float pg = seq[flow * (LPATH + 1) * DIM + pos * DIM + j];
        float att = ab;
#pragma unroll
        for (int k = 0; k < 16; ++k) att = fmaf(__shfl(pg, k, 16), wa[k], att);
        att = att > 0.f ? att : 0.01f * att;  // leaky_relu
        float m = att;
#pragma unroll
        for (int off = 8; off; off >>= 1) m = fmaxf(m, __shfl_xor(m, off, 16));
        float e = __expf(att - m);
        float s = e;
#pragma unroll
        for (int off = 8; off; off >>= 1) s += __shfl_xor(s, off, 16);
        acc = fmaf(e / s, pg, acc);
    }
    red[g][j] = acc;
    __syncthreads();
    if (tid < 16) {
        float ps = 0.f;
#pragma unroll
        for (int gg = 0; gg < 16; ++gg) ps += red[gg][j];
        float h = link_state[link * DIM + j];
        float az = b[j], ar = b[16 + j], ah = b[32 + j];
        float gz = b[48 + j], gr = b[64 + j], gh = b[80 + j];
#pragma unroll
        for (int k = 0; k < 16; ++k) {
            float xb = __shfl(ps, k, 16);
            float hb = __shfl(h, k, 16);
            az = fmaf(xb, Wk[k * 48 + j], az);
            ar = fmaf(xb, Wk[k * 48 + 16 + j], ar);
            ah = fmaf(xb, Wk[k * 48 + 32 + j], ah);
            gz = fmaf(hb, Wr[k * 48 + j], gz);
            gr = fmaf(hb, Wr[k * 48 + 16 + j], gr);
            gh = fmaf(hb, Wr[k * 48 + 32 + j], gh);
        }
        float z = sigmoid_(az + gz);
        float r = sigmoid_(ar + gr);
        float cand = tanh_(fmaf(r, gh, ah));
        float hn = z * h + (1.f - z) * cand;
        link_state[link * DIM + j] = hn;
        hsh[j] = hn;
    }
    __syncthreads();
    // xform for next flow_pass (pgru x-part): threads 0..47, one output col each
    if (tid < 48) {
        extern __global__ void k_flow_pass(const int*, const float*, float*,
                                           float*, const float*, const float*);
        // (no-op decl above just to keep clang quiet about unused warning paths)
    }
    if (tid < 48) {
        // NOTE: Wk here is the PATH gru Wk, passed separately below as pWk via
        // the xWk pointer argument. See launch site.
    }
    // real xform computation uses pWk/pb passed through attW? -- handled by
    // dedicated arguments in the launcher version below.
    (void)xform;
}

// Separate tiny kernel: xform from current link_state (runs after k_link_pass).
// 5000*48 = 240000 outputs; thread per output col group.
__global__ __launch_bounds__(256) void k_xform(
    const float* __restrict__ link_state, const float* __restrict__ pWk,
    const float* __restrict__ pb, float* __restrict__ xform) {
    int idx = blockIdx.x * 256 + threadIdx.x;  // link*48 + c
    if (idx >= N_LINKS * 48) return;
    int l = idx / 48;
    int c = idx - l * 48;
    const float* h = link_state + l * DIM;
    float a = pb[c];
#pragma unroll
    for (int k = 0; k < DIM; ++k) a = fmaf(h[k], pWk[k * 48 + c], a);
    xform[idx] = a;
}

// ---- readout: MLP over seq[:,1:] -> softplus -> /cap -> sum over L -------
__global__ __launch_bounds__(256) void k_readout(
    const float* __restrict__ seq, const int* __restrict__ l2p,
    const float* __restrict__ link_capacity,
    const float* __restrict__ W1, const float* __restrict__ b1,
    const float* __restrict__ W2, const float* __restrict__ b2,
    const float* __restrict__ W3, const float* __restrict__ b3,
    float* __restrict__ out) {
    int tid = blockIdx.x * 256 + threadIdx.x;
    int f = tid >> 3;
    int t = tid & 7;  // handles sequence position t+1
    if (f >= N_FLOWS) return;
    const float* s = seq + f * (LPATH + 1) * DIM + (t + 1) * DIM;
    float h1[8];
#pragma unroll
    for (int m = 0; m < 8; ++m) {
        float a = b1[m];
#pragma unroll
        for (int k = 0; k < 16; ++k) a = fmaf(s[k], W1[k * 8 + m], a);
        h1[m] = selu_(a);
    }
    float h2[4];
#pragma unroll
    for (int q = 0; q < 4; ++q) {
        float a = b2[q];
#pragma unroll
        for (int m = 0; m < 8; ++m) a = fmaf(h1[m], W2[m * 4 + q], a);
        h2[q] = selu_(a);
    }
    float o = b3[0];
#pragma unroll
    for (int q = 0; q < 4; ++q) o = fmaf(h2[q], W3[q], o);
    o = softplus_(o);
    int link = l2p[f * LPATH + t];
    float v = o / link_capacity[link];
#pragma unroll
    for (int off = 4; off; off >>= 1) v += __shfl_xor(v, off, 8);
    if (t == 0) out[f] = v;
}

extern "C" void kernel_launch(void* const* d_in, const int* in_sizes, int n_in,
                              void* d_out, int out_size, void* d_ws, size_t ws_size,
                              hipStream_t stream) {
    const float* flow_traffic = (const float*)d_in[0];
    const float* flow_packets = (const float*)d_in[1];
    const float* max_link_load = (const float*)d_in[2];
    const float* flow_pkts_per_burst = (const float*)d_in[3];
    const float* flow_bitrate_per_burst = (const float*)d_in[4];
    const float* flow_packet_size = (const float*)d_in[5];
    const float* flow_type = (const float*)d_in[6];
    const float* flow_ipg_mean = (const float*)d_in[7];
    const float* ibg = (const float*)d_in[8];
    const float* flow_p90 = (const float*)d_in[9];
    const float* rate = (const float*)d_in[10];
    const float* flow_ipg_var = (const float*)d_in[11];
    const float* link_capacity = (const float*)d_in[12];
    const float* fe_W1 = (const float*)d_in[13];
    const float* fe_b1 = (const float*)d_in[14];
    const float* fe_W2 = (const float*)d_in[15];
    const float* fe_b2 = (const float*)d_in[16];
    const float* le_W1 = (const float*)d_in[17];
    const float* le_b1 = (const float*)d_in[18];
    const float* le_W2 = (const float*)d_in[19];
    const float* le_b2 = (const float*)d_in[20];
    const float* att_W = (const float*)d_in[21];
    const float* att_b = (const float*)d_in[22];
    const float* pgru_Wk = (const float*)d_in[23];
    const float* pgru_Wr = (const float*)d_in[24];
    const float* pgru_b = (const float*)d_in[25];
    const float* lgru_Wk = (const float*)d_in[26];
    const float* lgru_Wr = (const float*)d_in[27];
    const float* lgru_b = (const float*)d_in[28];
    const float* ro_W1 = (const float*)d_in[29];
    const float* ro_b1 = (const float*)d_in[30];
    const float* ro_W2 = (const float*)d_in[31];
    const float* ro_b2 = (const float*)d_in[32];
    const float* ro_W3 = (const float*)d_in[33];
    const float* ro_b3 = (const float*)d_in[34];
    const int* flow_length = (const int*)d_in[35];
    const int* l2p = (const int*)d_in[36];
    const int* p2l = (const int*)d_in[37];

    float* ws = (float*)d_ws;
    float* path_state = ws;                      // 800000
    float* link_state = ws + 800000;             // 80000
    float* seq = ws + 880000;                    // 7200000
    float* load = ws + 8080000;                  // 5000
    float* xform = ws + 8085000;                 // 240000
    if (ws_size < (size_t)8325000 * 4) return;   // loud failure if ws too small

    k_load<<<(N_LINKS * 64 + 255) / 256, 256, 0, stream>>>(p2l, flow_traffic,
                                                           link_capacity, load);
    k_flow_init<<<(N_FLOWS + 255) / 256, 256, 0, stream>>>(
        flow_traffic, flow_packets, ibg, rate, flow_p90, flow_packet_size,
        flow_bitrate_per_burst, flow_ipg_mean, flow_ipg_var, flow_pkts_per_burst,
        flow_length, flow_type, fe_W1, fe_b1, fe_W2, fe_b2, path_state);
    k_link_init<<<(N_LINKS + 255) / 256, 256, 0, stream>>>(
        link_capacity, load, max_link_load, le_W1, le_b1, le_W2, le_b2,
        pgru_Wk, pgru_b, link_state, xform);

    for (int it = 0; it < ITERS; ++it) {
        k_flow_pass<<<N_FLOWS * 16 / 256, 256, 0, stream>>>(
            l2p, xform, path_state, seq, pgru_Wr, pgru_b);
        k_link_pass<<<N_LINKS, 256, 0, stream>>>(
            p2l, seq, link_state, att_W, att_b, lgru_Wk, lgru_Wr, lgru_b, xform);
        if (it < ITERS - 1)
            k_xform<<<(N_LINKS * 48 + 255) / 256, 256, 0, stream>>>(
                link_state, pgru_Wk, pgru_b, xform);
    }

    k_readout<<<(N_FLOWS * 8 + 255) / 256, 256, 0, stream>>>(
        seq, l2p, link_capacity, ro_W1, ro_b1, ro_W2, ro_b2, ro_W3, ro_b3,
        (float*)d_out);
}

// Round 3
// 639.736 us; speedup vs baseline: 1.4675x; 1.1333x over previous
//
#include <hip/hip_runtime.h>
#include <hip/hip_bf16.h>

#define N_FLOWS 50000
#define N_LINKS 5000
#define LPATH 8
#define PLINK 80
#define DIM 16
#define ITERS 12

// ds_swizzle BitMode: offset = (xor<<10) | (or<<5) | and  (within 32-lane half)
#define SWZ(x, pat) __int_as_float(__builtin_amdgcn_ds_swizzle(__float_as_int(x), (pat)))

__device__ __forceinline__ float sigmoid_(float x) { return 1.f / (1.f + __expf(-x)); }
__device__ __forceinline__ float tanh_(float x) { return 1.f - 2.f / (1.f + __expf(2.f * x)); }
__device__ __forceinline__ float selu_(float x) {
    const float sc = 1.0507009873554805f, al = 1.6732632423543772f;
    return x > 0.f ? sc * x : sc * al * expm1f(x);
}
__device__ __forceinline__ float softplus_(float x) {
    return fmaxf(x, 0.f) + log1pf(__expf(-fabsf(x)));
}

__device__ __forceinline__ void ld_row16(const float* row, float* dst) {
    float4 a = ((const float4*)row)[0];
    float4 b = ((const float4*)row)[1];
    float4 c = ((const float4*)row)[2];
    float4 d = ((const float4*)row)[3];
    dst[0] = a.x; dst[1] = a.y; dst[2] = a.z; dst[3] = a.w;
    dst[4] = b.x; dst[5] = b.y; dst[6] = b.z; dst[7] = b.w;
    dst[8] = c.x; dst[9] = c.y; dst[10] = c.z; dst[11] = c.w;
    dst[12] = d.x; dst[13] = d.y; dst[14] = d.z; dst[15] = d.w;
}

// ---- load per link: sum of gathered flow_traffic / (cap*1e9) -------------
__global__ __launch_bounds__(256) void k_load(const int* __restrict__ p2l,
                                              const float* __restrict__ flow_traffic,
                                              const float* __restrict__ link_capacity,
                                              float* __restrict__ load) {
    int wave = (blockIdx.x * 256 + threadIdx.x) >> 6;
    int lane = threadIdx.x & 63;
    if (wave >= N_LINKS) return;
    float s = 0.f;
    for (int p = lane; p < PLINK; p += 64) {
        int flow = p2l[(wave * PLINK + p) * 2];
        s += flow_traffic[flow];
    }
#pragma unroll
    for (int off = 32; off; off >>= 1) s += __shfl_xor(s, off, 64);
    if (lane == 0) load[wave] = s / (link_capacity[wave] * 1e9f);
}

// ---- flow embedding: feats(13) -> selu -> selu -> path_state(16) ---------
__global__ __launch_bounds__(256) void k_flow_init(
    const float* __restrict__ flow_traffic, const float* __restrict__ flow_packets,
    const float* __restrict__ ibg, const float* __restrict__ rate,
    const float* __restrict__ p90, const float* __restrict__ pkt_size,
    const float* __restrict__ bitrate_pb, const float* __restrict__ ipg_mean,
    const float* __restrict__ ipg_var, const float* __restrict__ pkts_pb,
    const int* __restrict__ flow_length, const float* __restrict__ flow_type,
    const float* __restrict__ W1, const float* __restrict__ b1,
    const float* __restrict__ W2, const float* __restrict__ b2,
    float* __restrict__ path_state) {
    int f = blockIdx.x * 256 + threadIdx.x;
    if (f >= N_FLOWS) return;
    float feats[13];
    feats[0] = (flow_traffic[f] - 0.1f) * 2.f;
    feats[1] = (flow_packets[f] - 0.1f) * 2.f;
    feats[2] = (ibg[f] - 0.1f) * 2.f;
    feats[3] = (rate[f] - 0.1f) * 2.f;
    feats[4] = (p90[f] - 0.1f) * 2.f;
    feats[5] = (pkt_size[f] - 0.1f) * 2.f;
    feats[6] = (bitrate_pb[f] - 0.1f) * 2.f;
    feats[7] = (ipg_mean[f] - 0.1f) * 2.f;
    feats[8] = (ipg_var[f] - 0.1f) * 2.f;
    feats[9] = (pkts_pb[f] - 0.1f) * 2.f;
    feats[10] = (float)flow_length[f];
    feats[11] = flow_type[f * 2 + 0];
    feats[12] = flow_type[f * 2 + 1];
    float h1[DIM];
#pragma unroll
    for (int j = 0; j < DIM; ++j) {
        float a = b1[j];
#pragma unroll
        for (int k = 0; k < 13; ++k) a = fmaf(feats[k], W1[k * DIM + j], a);
        h1[j] = selu_(a);
    }
#pragma unroll
    for (int j = 0; j < DIM; ++j) {
        float a = b2[j];
#pragma unroll
        for (int k = 0; k < DIM; ++k) a = fmaf(h1[k], W2[k * DIM + j], a);
        path_state[f * DIM + j] = selu_(a);
    }
}

// ---- link embedding + xform precompute -----------------------------------
__global__ __launch_bounds__(256) void k_link_init(
    const float* __restrict__ link_capacity, const float* __restrict__ load,
    const float* __restrict__ max_link_load,
    const float* __restrict__ W1, const float* __restrict__ b1,
    const float* __restrict__ W2, const float* __restrict__ b2,
    const float* __restrict__ pWk, const float* __restrict__ pb,
    float* __restrict__ link_state, float* __restrict__ xform) {
    int l = blockIdx.x * 256 + threadIdx.x;
    if (l >= N_LINKS) return;
    float feats[3];
    feats[0] = (link_capacity[l] - 0.1f) * 2.f;
    feats[1] = load[l];
    feats[2] = load[l] / max_link_load[0];
    float h1[DIM];
#pragma unroll
    for (int j = 0; j < DIM; ++j) {
        float a = b1[j];
#pragma unroll
        for (int k = 0; k < 3; ++k) a = fmaf(feats[k], W1[k * DIM + j], a);
        h1[j] = selu_(a);
    }
    float h2[DIM];
#pragma unroll
    for (int j = 0; j < DIM; ++j) {
        float a = b2[j];
#pragma unroll
        for (int k = 0; k < DIM; ++k) a = fmaf(h1[k], W2[k * DIM + j], a);
        h2[j] = selu_(a);
        link_state[l * DIM + j] = h2[j];
    }
#pragma unroll
    for (int c = 0; c < 3 * DIM; ++c) {
        float a = pb[c];
#pragma unroll
        for (int k = 0; k < DIM; ++k) a = fmaf(h2[k], pWk[k * 48 + c], a);
        xform[l * 48 + c] = a;
    }
}

// ---- flow pass: GRU scan + fused per-(flow,pos) attention softmax --------
// 16 lanes per flow. Writes sv[pos][flow][j] = softmax_j(leaky(h@attW+b)) * h_j.
// LAST=true: skips sv, keeps history in LDS, fuses the readout MLP.
template <bool LAST>
__global__ __launch_bounds__(256, 4) void k_flow_pass(
    const int* __restrict__ l2p, const float* __restrict__ xform,
    float* __restrict__ path_state, float* __restrict__ sv,
    const float* __restrict__ Wr, const float* __restrict__ b,
    const float* __restrict__ attW, const float* __restrict__ attB,
    const float* __restrict__ link_capacity,
    const float* __restrict__ roW1, const float* __restrict__ rob1,
    const float* __restrict__ roW2, const float* __restrict__ rob2,
    const float* __restrict__ roW3, const float* __restrict__ rob3,
    float* __restrict__ out) {
    __shared__ float hbuf[16][16];
    __shared__ float shist[LAST ? 16 : 1][LPATH + 1][17];
    int tid = threadIdx.x;
    int gi = tid >> 4, j = tid & 15;
    int f = blockIdx.x * 16 + gi;  // 50000 % 16 == 0 with grid 3125 -> exact
    float wrz[16], wrr[16], wrh[16], wa[16];
#pragma unroll
    for (int k = 0; k < 16; ++k) {
        wrz[k] = Wr[k * 48 + j];
        wrr[k] = Wr[k * 48 + 16 + j];
        wrh[k] = Wr[k * 48 + 32 + j];
        wa[k] = attW[k * DIM + j];
    }
    float b1z = b[48 + j], b1r = b[64 + j], b1h = b[80 + j], ab = attB[j];
    int links[LPATH];
#pragma unroll
    for (int t = 0; t < LPATH; ++t) links[t] = l2p[f * LPATH + t];
    float h = path_state[f * DIM + j];
    float nz = xform[links[0] * 48 + j];
    float nr = xform[links[0] * 48 + 16 + j];
    float nh = xform[links[0] * 48 + 32 + j];
#pragma unroll
    for (int p = 0; p <= LPATH; ++p) {
        // broadcast h across the 16-lane group via LDS (1 write + 4x b128 read)
        hbuf[gi][j] = h;
        float hb[16];
        ld_row16(hbuf[gi], hb);
        if (!LAST) {
            float att = ab;
#pragma unroll
            for (int k = 0; k < 16; ++k) att = fmaf(hb[k], wa[k], att);
            att = att > 0.f ? att : 0.01f * att;  // leaky_relu
            float m = att;
            m = fmaxf(m, SWZ(m, 0x041F));
            m = fmaxf(m, SWZ(m, 0x081F));
            m = fmaxf(m, SWZ(m, 0x101F));
            m = fmaxf(m, SWZ(m, 0x201F));
            float e = __expf(att - m);
            float s = e;
            s += SWZ(s, 0x041F);
            s += SWZ(s, 0x081F);
            s += SWZ(s, 0x101F);
            s += SWZ(s, 0x201F);
            sv[p * (N_FLOWS * DIM) + f * DIM + j] = (e / s) * h;
        } else {
            shist[gi][p][j] = h;
        }
        if (p < LPATH) {
            float az = nz, ar = nr, ah = nh;
            if (p + 1 < LPATH) {
                nz = xform[links[p + 1] * 48 + j];
                nr = xform[links[p + 1] * 48 + 16 + j];
                nh = xform[links[p + 1] * 48 + 32 + j];
            }
            float gz = b1z, gr = b1r, gh = b1h;
#pragma unroll
            for (int k = 0; k < 16; ++k) {
                gz = fmaf(hb[k], wrz[k], gz);
                gr = fmaf(hb[k], wrr[k], gr);
                gh = fmaf(hb[k], wrh[k], gh);
            }
            float z = sigmoid_(az + gz);
            float r = sigmoid_(ar + gr);
            float cand = tanh_(fmaf(r, gh, ah));
            h = z * h + (1.f - z) * cand;
        }
    }
    if (!LAST) {
        path_state[f * DIM + j] = h;
    } else {
        __syncthreads();
        if (tid < 128) {  // 16 flows x 8 positions; 2 full waves
            int fl = tid >> 3, t = tid & 7;
            int fg = blockIdx.x * 16 + fl;
            const float* s = shist[fl][t + 1];
            float h1[8];
#pragma unroll
            for (int m_ = 0; m_ < 8; ++m_) {
                float a = rob1[m_];
#pragma unroll
                for (int k = 0; k < 16; ++k) a = fmaf(s[k], roW1[k * 8 + m_], a);
                h1[m_] = selu_(a);
            }
            float h2[4];
#pragma unroll
            for (int q = 0; q < 4; ++q) {
                float a = rob2[q];
#pragma unroll
                for (int m_ = 0; m_ < 8; ++m_) a = fmaf(h1[m_], roW2[m_ * 4 + q], a);
                h2[q] = selu_(a);
            }
            float o = rob3[0];
#pragma unroll
            for (int q = 0; q < 4; ++q) o = fmaf(h2[q], roW3[q], o);
            o = softplus_(o);
            int link = l2p[fg * LPATH + t];
            float v = o / link_capacity[link];
            v += SWZ(v, 0x041F);
            v += SWZ(v, 0x081F);
            v += SWZ(v, 0x101F);
            if (t == 0) out[fg] = v;
        }
    }
}

// ---- link pass: gather-sum of precomputed sv + link GRU + fused xform ----
// 4 links per 256-block, one wave per link (16 j-lanes x 4 p-slices).
__global__ __launch_bounds__(256, 4) void k_link_pass(
    const int* __restrict__ p2l, const float* __restrict__ sv,
    float* __restrict__ link_state,
    const float* __restrict__ Wk, const float* __restrict__ Wr,
    const float* __restrict__ b,
    const float* __restrict__ pWk, const float* __restrict__ pb,
    float* __restrict__ xform) {
    __shared__ float xb_[4][16];
    __shared__ float hb_[4][16];
    int tid = threadIdx.x;
    int li = tid >> 6;
    int lane = tid & 63;
    int sl = lane >> 4, j = lane & 15;
    int link = blockIdx.x * 4 + li;
    float ps = 0.f;
#pragma unroll 4
    for (int i = 0; i < PLINK / 4; ++i) {
        int p = sl + 4 * i;
        int2 fp = ((const int2*)p2l)[link * PLINK + p];
        ps += sv[fp.y * (N_FLOWS * DIM) + fp.x * DIM + j];
    }
    ps += __shfl_xor(ps, 16, 64);
    ps += __shfl_xor(ps, 32, 64);
    float h = link_state[link * DIM + j];
    if (sl == 0) { xb_[li][j] = ps; hb_[li][j] = h; }
    float xv[16], hv[16];
    ld_row16(xb_[li], xv);
    ld_row16(hb_[li], hv);
    float az = b[j], ar = b[16 + j], ah = b[32 + j];
    float gz = b[48 + j], gr = b[64 + j], gh = b[80 + j];
#pragma unroll
    for (int k = 0; k < 16; ++k) {
        az = fmaf(xv[k], Wk[k * 48 + j], az);
        ar = fmaf(xv[k], Wk[k * 48 + 16 + j], ar);
        ah = fmaf(xv[k], Wk[k * 48 + 32 + j], ah);
        gz = fmaf(hv[k], Wr[k * 48 + j], gz);
        gr = fmaf(hv[k], Wr[k * 48 + 16 + j], gr);
        gh = fmaf(hv[k], Wr[k * 48 + 32 + j], gh);
    }
    float z = sigmoid_(az + gz);
    float r = sigmoid_(ar + gr);
    float hn = z * h + (1.f - z) * tanh_(fmaf(r, gh, ah));
    if (sl == 0) {
        link_state[link * DIM + j] = hn;
        hb_[li][j] = hn;  // re-broadcast new state for xform
    }
    float nv[16];
    ld_row16(hb_[li], nv);
    int c = lane;
    if (c < 48) {
        float a = pb[c];
#pragma unroll
        for (int k = 0; k < 16; ++k) a = fmaf(nv[k], pWk[k * 48 + c], a);
        xform[link * 48 + c] = a;
    }
}

extern "C" void kernel_launch(void* const* d_in, const int* in_sizes, int n_in,
                              void* d_out, int out_size, void* d_ws, size_t ws_size,
                              hipStream_t stream) {
    const float* flow_traffic = (const float*)d_in[0];
    const float* flow_packets = (const float*)d_in[1];
    const float* max_link_load = (const float*)d_in[2];
    const float* flow_pkts_per_burst = (const float*)d_in[3];
    const float* flow_bitrate_per_burst = (const float*)d_in[4];
    const float* flow_packet_size = (const float*)d_in[5];
    const float* flow_type = (const float*)d_in[6];
    const float* flow_ipg_mean = (const float*)d_in[7];
    const float* ibg = (const float*)d_in[8];
    const float* flow_p90 = (const float*)d_in[9];
    const float* rate = (const float*)d_in[10];
    const float* flow_ipg_var = (const float*)d_in[11];
    const float* link_capacity = (const float*)d_in[12];
    const float* fe_W1 = (const float*)d_in[13];
    const float* fe_b1 = (const float*)d_in[14];
    const float* fe_W2 = (const float*)d_in[15];
    const float* fe_b2 = (const float*)d_in[16];
    const float* le_W1 = (const float*)d_in[17];
    const float* le_b1 = (const float*)d_in[18];
    const float* le_W2 = (const float*)d_in[19];
    const float* le_b2 = (const float*)d_in[20];
    const float* att_W = (const float*)d_in[21];
    const float* att_b = (const float*)d_in[22];
    const float* pgru_Wk = (const float*)d_in[23];
    const float* pgru_Wr = (const float*)d_in[24];
    const float* pgru_b = (const float*)d_in[25];
    const float* lgru_Wk = (const float*)d_in[26];
    const float* lgru_Wr = (const float*)d_in[27];
    const float* lgru_b = (const float*)d_in[28];
    const float* ro_W1 = (const float*)d_in[29];
    const float* ro_b1 = (const float*)d_in[30];
    const float* ro_W2 = (const float*)d_in[31];
    const float* ro_b2 = (const float*)d_in[32];
    const float* ro_W3 = (const float*)d_in[33];
    const float* ro_b3 = (const float*)d_in[34];
    const int* flow_length = (const int*)d_in[35];
    const int* l2p = (const int*)d_in[36];
    const int* p2l = (const int*)d_in[37];

    float* ws = (float*)d_ws;
    float* path_state = ws;                      // 800000
    float* link_state = ws + 800000;             // 80000
    float* sv = ws + 880000;                     // 7200000  [pos][flow][16]
    float* load = ws + 8080000;                  // 5000
    float* xform = ws + 8085000;                 // 240000
    if (ws_size < (size_t)8325000 * 4) return;

    k_load<<<(N_LINKS * 64 + 255) / 256, 256, 0, stream>>>(p2l, flow_traffic,
                                                           link_capacity, load);
    k_flow_init<<<(N_FLOWS + 255) / 256, 256, 0, stream>>>(
        flow_traffic, flow_packets, ibg, rate, flow_p90, flow_packet_size,
        flow_bitrate_per_burst, flow_ipg_mean, flow_ipg_var, flow_pkts_per_burst,
        flow_length, flow_type, fe_W1, fe_b1, fe_W2, fe_b2, path_state);
    k_link_init<<<(N_LINKS + 255) / 256, 256, 0, stream>>>(
        link_capacity, load, max_link_load, le_W1, le_b1, le_W2, le_b2,
        pgru_Wk, pgru_b, link_state, xform);

    for (int it = 0; it < ITERS - 1; ++it) {
        k_flow_pass<false><<<N_FLOWS / 16, 256, 0, stream>>>(
            l2p, xform, path_state, sv, pgru_Wr, pgru_b, att_W, att_b,
            nullptr, nullptr, nullptr, nullptr, nullptr, nullptr, nullptr,
            nullptr);
        k_link_pass<<<N_LINKS / 4, 256, 0, stream>>>(
            p2l, sv, link_state, lgru_Wk, lgru_Wr, lgru_b, pgru_Wk, pgru_b,
            xform);
    }
    // final iteration: no sv / no link update needed; fuse readout.
    k_flow_pass<true><<<N_FLOWS / 16, 256, 0, stream>>>(
        l2p, xform, path_state, sv, pgru_Wr, pgru_b, att_W, att_b,
        link_capacity, ro_W1, ro_b1, ro_W2, ro_b2, ro_W3, ro_b3,
        (float*)d_out);
}